// Round 1
// baseline (537.054 us; speedup 1.0000x reference)
//
#include <hip/hip_runtime.h>

// LSTM (B=2048, T=1024, I=8, H=64) + sigmoid(FC), bf16 MFMA, in-register
// activations, duplicate-column split, 2 blocks/CU.
//
// R=4 batch rows/block -> 512 blocks = 2/CU (launch_bounds(256,2)); the two
// co-resident blocks cover each other's barrier + latency shadows.
// Wave wv owns gate-strided M-tiles {4g+wv}; thread activates ONE element
// (jh = 16wv+4g4+rsel) via a hoisted cndmask tree.
//
// This revision vs. previous:
//  - raw s_barrier + explicit lgkmcnt(0) (no vmcnt(0) drain per step; the
//    chunk's global_load floats 30 steps until stage_write uses it)
//  - x-projection MFMAs pipelined ACROSS the barrier: during step t we
//    prefetch fx(t+1) and refill acc with the x-part, so the post-barrier
//    critical path is only ds_read(fh) -> 8 h-MFMAs -> select -> act.
//    stage_write moved to tt==30 so buf^1[0] is barrier-visible at tt==31.
//  - exp2-folded activations (sign/log2e folded into one v_mul per transc)
//  - v_cvt_pk_bf16_f32 (1 op, RNE) replaces manual round-to-bf16
//  - h_lds stride 40 -> 80 shorts: rows no longer overlap (jh reaches 63)
//    and fh reads land on uniform 2-way banks (free) instead of 3-way
//  - inner tt loop unrolled x4: hb parity compile-time, ds offsets immediate

namespace {
constexpr int T_LEN = 1024;
constexpr int R     = 4;    // batch rows per block
constexpr int TS    = 32;   // timesteps of x per staged chunk
constexpr int HP    = 80;   // h_lds row stride in shorts (160 B, 16B-aligned)
constexpr float L2E = 1.4426950408889634f;

typedef __attribute__((ext_vector_type(8))) short  short8v;
typedef __attribute__((ext_vector_type(4))) float  float4v;
typedef unsigned short u16;
typedef unsigned long long u64;

__device__ __forceinline__ float fsig(float x) {
  // 1/(1+exp(-x)) = rcp(1 + exp2(x * -log2e)) : 2 full-rate + 2 transc ops
  return __builtin_amdgcn_rcpf(1.f + exp2f(-L2E * x));
}
__device__ __forceinline__ float ftanh(float x) {
  // tanh(x) = 1 - 2*rcp(exp2(2*log2e*x) + 1) : 3 full-rate + 2 transc ops
  const float r = __builtin_amdgcn_rcpf(exp2f((2.f * L2E) * x) + 1.f);
  return __builtin_fmaf(-2.f, r, 1.f);
}
__device__ __forceinline__ u16 f2bf(float f) {  // RNE (init-time only)
  unsigned int u = __float_as_uint(f);
  unsigned int r = ((u >> 16) & 1u) + 0x7fffu;
  return (u16)((u + r) >> 16);
}
__device__ __forceinline__ u16 cvt_bf16(float f) {  // 1 VALU op, RNE
  unsigned int d;
  asm("v_cvt_pk_bf16_f32 %0, %1, %2" : "=v"(d) : "v"(f), "v"(f));
  return (u16)d;
}
__device__ __forceinline__ void wave_barrier() {
  // __syncthreads() would force vmcnt(0) too, stalling on the chunk's
  // in-flight global loads. Only LDS (h + staged x) needs ordering here.
  asm volatile("s_waitcnt lgkmcnt(0)" ::: "memory");
  __builtin_amdgcn_s_barrier();
  asm volatile("" ::: "memory");  // block ds_read hoisting above the barrier
}

__global__ __launch_bounds__(256, 2) void lstm_split(
    const float* __restrict__ x,     // [B, T, 8]
    const float* __restrict__ W_ih,  // [256, 8]
    const float* __restrict__ W_hh,  // [256, 64]
    const float* __restrict__ b_ih,  // [256]
    const float* __restrict__ b_hh,  // [256]
    const float* __restrict__ fc_w,  // [64]
    const float* __restrict__ fc_b,  // [1]
    float* __restrict__ out) {       // [B]
  __shared__ __align__(16) u16   x_lds[2][TS][R][32];  // 16 KB; full K-rows
  __shared__ __align__(16) u16   h_lds[2][R][HP];      // 2.5 KB
  __shared__ __align__(16) float hf[R][64];            // final h (fp32)

  const int tid  = threadIdx.x;
  const int lane = tid & 63;
  const int wv   = tid >> 6;       // wave 0..3
  const int g4   = lane >> 4;      // MFMA k-quad / C row-quad
  const int nib  = lane & 15;      // MFMA m/n coord
  const int row  = nib & 3;        // batch row (cols 4..15 duplicate 0..3)
  const int rsel = nib >> 2;       // which acc reg this thread activates
  const int jh   = 16 * wv + 4 * g4 + rsel;  // owned h index
  const int bBase = blockIdx.x * R;

  // ---- static A fragments: wave wv holds tiles {4g+wv}, g=0..3 (i,f,g,o) ----
  short8v a0[4], a1[4], a2[4];
  for (int g = 0; g < 4; ++g) {
    const int n = 64 * g + 16 * wv + nib;  // gate row
    short8v f0, f1, f2;
    for (int j = 0; j < 8; ++j) {
      const int k = 8 * g4 + j;
      float v0 = 0.f;
      if (k < 8) v0 = W_ih[n * 8 + k];
      else if (k == 8) v0 = b_ih[n] + b_hh[n];
      f0[j] = (short)f2bf(v0);
      f1[j] = (short)f2bf(W_hh[n * 64 + k]);
      f2[j] = (short)f2bf(W_hh[n * 64 + 32 + k]);
    }
    a0[g] = f0; a1[g] = f1; a2[g] = f2;
  }

  // ---- LDS init: h0 = 0 (both bufs); x constant channels once per buf ----
  for (int i = tid; i < 2 * R * HP; i += 256) ((u16*)h_lds)[i] = 0;
  {  // 256 threads <-> 2 bufs x 32 tt x 4 rows
    const int buf = tid >> 7, rem = tid & 127, tt = rem >> 2, rr = rem & 3;
    u16* p = &x_lds[buf][tt][rr][0];
    p[8] = 0x3f80;  // bias channel = 1.0
    for (int chn = 9; chn < 32; ++chn) p[chn] = 0;
  }

  // ---- x staging: 1 float4/thread/chunk, double-buffered ----
  float4v xr;
  const int sr = tid >> 6, sm = tid & 63;          // src row, float4 idx
  const int stt = sm >> 1, sch = (sm & 1) * 4;     // dest tt, channel
  auto stage_load = [&](int chunk) {
    const float* src = x + ((size_t)bBase + sr) * (T_LEN * 8) +
                       (size_t)chunk * (TS * 8);
    xr = *(const float4v*)&src[sm * 4];
  };
  auto stage_write = [&](int buf) {
    unsigned lo, hi;
    asm("v_cvt_pk_bf16_f32 %0, %1, %2" : "=v"(lo) : "v"(xr[0]), "v"(xr[1]));
    asm("v_cvt_pk_bf16_f32 %0, %1, %2" : "=v"(hi) : "v"(xr[2]), "v"(xr[3]));
    const u64 p = ((u64)hi << 32) | (u64)lo;
    *(u64*)&x_lds[buf][stt][sr][sch] = p;
  };

  stage_load(0);
  stage_write(0);
  __syncthreads();

  // hoisted select masks for the cndmask tree
  const bool sel1 = (rsel & 1) != 0;
  const bool sel2 = (rsel & 2) != 0;

  // ---- prologue: acc <- x-projection for t=0 ----
  float4v acc[4];
  {
    const short8v fx = *(const short8v*)&x_lds[0][0][row][8 * g4];
#pragma unroll
    for (int g = 0; g < 4; ++g)
      acc[g] = __builtin_amdgcn_mfma_f32_16x16x32_bf16(
          a0[g], fx, (float4v){0.f, 0.f, 0.f, 0.f}, 0, 0, 0);
  }

  float c = 0.f;
  for (int ch = 0; ch < T_LEN / TS; ++ch) {
    const int xb = ch & 1;
    const bool more = (ch < T_LEN / TS - 1);
    if (more) stage_load(ch + 1);  // reg loads; vmcnt drains at stage_write
#pragma unroll 4
    for (int tt = 0; tt < TS; ++tt) {
      const int hb = tt & 1;  // compile-time under unroll

      // ---- post-barrier critical path: h fragments + 8 h-MFMAs ----
      const short8v fh0 = *(const short8v*)&h_lds[hb][row][8 * g4];
      const short8v fh1 = *(const short8v*)&h_lds[hb][row][32 + 8 * g4];
#pragma unroll
      for (int g = 0; g < 4; ++g)
        acc[g] = __builtin_amdgcn_mfma_f32_16x16x32_bf16(a1[g], fh0, acc[g], 0, 0, 0);
#pragma unroll
      for (int g = 0; g < 4; ++g)
        acc[g] = __builtin_amdgcn_mfma_f32_16x16x32_bf16(a2[g], fh1, acc[g], 0, 0, 0);

      // ---- pick this thread's element (reg-select tree) ----
      float gsel[4];
#pragma unroll
      for (int g = 0; g < 4; ++g) {
        const float x01 = sel1 ? acc[g][1] : acc[g][0];
        const float x23 = sel1 ? acc[g][3] : acc[g][2];
        gsel[g] = sel2 ? x23 : x01;
      }

      // ---- pipelined x-projection for t+1 (independent of act chain;
      //      issues under the transcendental latency, retires pre-barrier).
      //      tt==TS-1 reads buf^1[0], made visible by tt==TS-2's
      //      stage_write + barrier. ----
      const bool last = (!more) && (tt == TS - 1);
      if (!last) {
        const u16* nx = (tt < TS - 1) ? &x_lds[xb][tt + 1][row][8 * g4]
                                      : &x_lds[xb ^ 1][0][row][8 * g4];
        const short8v fx = *(const short8v*)nx;
#pragma unroll
        for (int g = 0; g < 4; ++g)
          acc[g] = __builtin_amdgcn_mfma_f32_16x16x32_bf16(
              a0[g], fx, (float4v){0.f, 0.f, 0.f, 0.f}, 0, 0, 0);
      }

      // ---- activate (exp2-folded) ----
      const float iv = fsig(gsel[0]);
      const float fv = fsig(gsel[1]);
      const float gv = ftanh(gsel[2]);
      const float ov = fsig(gsel[3]);
      c = __builtin_fmaf(fv, c, iv * gv);
      const float h = ov * ftanh(c);
      h_lds[hb ^ 1][row][jh] = cvt_bf16(h);
      if (!more && tt == TS - 1) hf[row][jh] = h;
      if (tt == TS - 2 && more) stage_write(xb ^ 1);  // before barrier: visible at tt+1
      wave_barrier();  // lgkmcnt(0) + s_barrier only
    }
  }
  __syncthreads();

  // ---- epilogue: out[b] = sigmoid(hT . fc_w + fc_b) ----
  if (tid < R) {
    float a = fc_b[0];
#pragma unroll
    for (int k = 0; k < 64; ++k) a += hf[tid][k] * fc_w[k];
    out[bBase + tid] = fsig(a);
  }
}
}  // namespace

extern "C" void kernel_launch(void* const* d_in, const int* in_sizes, int n_in,
                              void* d_out, int out_size, void* d_ws,
                              size_t ws_size, hipStream_t stream) {
  const float* x    = (const float*)d_in[0];
  const float* W_ih = (const float*)d_in[1];
  const float* W_hh = (const float*)d_in[2];
  const float* b_ih = (const float*)d_in[3];
  const float* b_hh = (const float*)d_in[4];
  const float* fc_w = (const float*)d_in[5];
  const float* fc_b = (const float*)d_in[6];
  float* out = (float*)d_out;

  const int B = in_sizes[0] / (T_LEN * 8);  // 2048
  lstm_split<<<dim3(B / R), dim3(256), 0, stream>>>(x, W_ih, W_hh, b_ih, b_hh,
                                                    fc_w, fc_b, out);
}

// Round 2
// 516.633 us; speedup vs baseline: 1.0395x; 1.0395x over previous
//
#include <hip/hip_runtime.h>

// LSTM (B=2048, T=1024, I=8, H=64) + sigmoid(FC), bf16 MFMA, in-register
// activations, duplicate-column split, 2 blocks/CU.
//
// R=4 batch rows/block -> 512 blocks = 2/CU (launch_bounds(256,2)); the two
// co-resident blocks cover each other's barrier + latency shadows.
// MFMA N-columns: col nib carries batch row nib&3 (4 duplicate groups).
// Wave wv owns gate-strided M-tiles {4g+wv}: acc[g][r] = gate quarter g of
// h-index jh = 16wv+4g4+r, col nib. Thread activates ONE element, picking
// r = rsel = nib>>2 from its acc regs via a hoisted cndmask tree.
// x is staged as full 32-wide K-rows [tt][row][32] with ch8=1.0 (bias) and
// ch9..31=0 prefilled once -> fx is one uniform ds_read_b128, no select.
// Per step: 3 ds_read_b128 -> 12 MFMA -> 1-elem act -> ds_write_b16 -> barrier.
//
// r2 (this revision) = r0 structure + the two counter-verified r1 wins:
//  - h_lds stride 40 -> 80 shorts (bank conflicts 1.88e7 -> 2.0e6 measured);
//    rows disjoint, fh reads on uniform free 2-way banks
//  - exp2-folded activations (log2e/sign folded into one v_mul per transc)
//    and v_cvt_pk_bf16_f32 (1 VALU op, RNE) for bf16 stores
//  - full unroll of the tt loop (compile-time hb parity / ds offsets);
//    r1's partial unroll + raw-asm barriers regressed and are reverted

namespace {
constexpr int T_LEN = 1024;
constexpr int R     = 4;    // batch rows per block
constexpr int TS    = 32;   // timesteps of x per staged chunk
constexpr int HP    = 80;   // h_lds row stride in shorts (160 B, 16B-aligned)
constexpr float L2E = 1.4426950408889634f;

typedef __attribute__((ext_vector_type(8))) short  short8v;
typedef __attribute__((ext_vector_type(4))) float  float4v;
typedef unsigned short u16;
typedef unsigned long long u64;

__device__ __forceinline__ float fsig(float x) {
  // 1/(1+exp(-x)) = rcp(1 + exp2(x * -log2e))
  return __builtin_amdgcn_rcpf(1.f + exp2f(-L2E * x));
}
__device__ __forceinline__ float ftanh(float x) {
  // tanh(x) = 1 - 2*rcp(exp2(2*log2e*x) + 1)
  const float r = __builtin_amdgcn_rcpf(exp2f((2.f * L2E) * x) + 1.f);
  return __builtin_fmaf(-2.f, r, 1.f);
}
__device__ __forceinline__ u16 f2bf(float f) {  // RNE (init-time only)
  unsigned int u = __float_as_uint(f);
  unsigned int r = ((u >> 16) & 1u) + 0x7fffu;
  return (u16)((u + r) >> 16);
}
__device__ __forceinline__ u16 cvt_bf16(float f) {  // 1 VALU op, RNE
  unsigned int d;
  asm("v_cvt_pk_bf16_f32 %0, %1, %2" : "=v"(d) : "v"(f), "v"(f));
  return (u16)d;
}

__global__ __launch_bounds__(256, 2) void lstm_split(
    const float* __restrict__ x,     // [B, T, 8]
    const float* __restrict__ W_ih,  // [256, 8]
    const float* __restrict__ W_hh,  // [256, 64]
    const float* __restrict__ b_ih,  // [256]
    const float* __restrict__ b_hh,  // [256]
    const float* __restrict__ fc_w,  // [64]
    const float* __restrict__ fc_b,  // [1]
    float* __restrict__ out) {       // [B]
  __shared__ __align__(16) u16   x_lds[2][TS][R][32];  // 16 KB; full K-rows
  __shared__ __align__(16) u16   h_lds[2][R][HP];      // 2.5 KB
  __shared__ __align__(16) float hf[R][64];            // final h (fp32)

  const int tid  = threadIdx.x;
  const int lane = tid & 63;
  const int wv   = tid >> 6;       // wave 0..3
  const int g4   = lane >> 4;      // MFMA k-quad / C row-quad
  const int nib  = lane & 15;      // MFMA m/n coord
  const int row  = nib & 3;        // batch row (cols 4..15 duplicate 0..3)
  const int rsel = nib >> 2;       // which acc reg this thread activates
  const int jh   = 16 * wv + 4 * g4 + rsel;  // owned h index
  const int bBase = blockIdx.x * R;

  // ---- static A fragments: wave wv holds tiles {4g+wv}, g=0..3 (i,f,g,o) ----
  // A[m=16*(4g+wv)+nib][k=8*g4+j]; frag0 k=0..31 = [W_ih(8)|bias|0...],
  // frag1 = W_hh[:,0:32], frag2 = W_hh[:,32:64].
  short8v a0[4], a1[4], a2[4];
  for (int g = 0; g < 4; ++g) {
    const int n = 64 * g + 16 * wv + nib;  // gate row
    short8v f0, f1, f2;
    for (int j = 0; j < 8; ++j) {
      const int k = 8 * g4 + j;
      float v0 = 0.f;
      if (k < 8) v0 = W_ih[n * 8 + k];
      else if (k == 8) v0 = b_ih[n] + b_hh[n];
      f0[j] = (short)f2bf(v0);
      f1[j] = (short)f2bf(W_hh[n * 64 + k]);
      f2[j] = (short)f2bf(W_hh[n * 64 + 32 + k]);
    }
    a0[g] = f0; a1[g] = f1; a2[g] = f2;
  }

  // ---- LDS init: h0 = 0 (both bufs); x constant channels once per buf ----
  for (int i = tid; i < 2 * R * HP; i += 256) ((u16*)h_lds)[i] = 0;
  {  // 256 threads <-> 2 bufs x 32 tt x 4 rows
    const int buf = tid >> 7, rem = tid & 127, tt = rem >> 2, rr = rem & 3;
    u16* p = &x_lds[buf][tt][rr][0];
    p[8] = 0x3f80;  // bias channel = 1.0
    for (int chn = 9; chn < 32; ++chn) p[chn] = 0;
  }

  // ---- x staging: 1 float4/thread/chunk, double-buffered ----
  float4v xr;
  const int sr = tid >> 6, sm = tid & 63;          // src row, float4 idx
  const int stt = sm >> 1, sch = (sm & 1) * 4;     // dest tt, channel
  auto stage_load = [&](int chunk) {
    const float* src = x + ((size_t)bBase + sr) * (T_LEN * 8) +
                       (size_t)chunk * (TS * 8);
    xr = *(const float4v*)&src[sm * 4];
  };
  auto stage_write = [&](int buf) {
    unsigned lo, hi;
    asm("v_cvt_pk_bf16_f32 %0, %1, %2" : "=v"(lo) : "v"(xr[0]), "v"(xr[1]));
    asm("v_cvt_pk_bf16_f32 %0, %1, %2" : "=v"(hi) : "v"(xr[2]), "v"(xr[3]));
    const u64 p = ((u64)hi << 32) | (u64)lo;
    *(u64*)&x_lds[buf][stt][sr][sch] = p;
  };

  stage_load(0);
  stage_write(0);
  __syncthreads();

  // hoisted select masks for the cndmask tree
  const bool sel1 = (rsel & 1) != 0;
  const bool sel2 = (rsel & 2) != 0;
  float c = 0.f;

  for (int ch = 0; ch < T_LEN / TS; ++ch) {
    const int xb = ch & 1;
    const bool more = (ch < T_LEN / TS - 1);
#pragma unroll
    for (int tt = 0; tt < TS; ++tt) {
      const int t = ch * TS + tt;
      const int hb = tt & 1;  // == t & 1 (TS even); compile-time under unroll
      if (tt == 0 && more) stage_load(ch + 1);  // reg loads; drain in stage_write

      // ---- B fragments (uniform b128 reads) ----
      const short8v fx  = *(const short8v*)&x_lds[xb][tt][row][8 * g4];
      const short8v fh0 = *(const short8v*)&h_lds[hb][row][8 * g4];
      const short8v fh1 = *(const short8v*)&h_lds[hb][row][32 + 8 * g4];

      // ---- 12 MFMAs: 4 gate-quads x (x | h-lo | h-hi) ----
      float4v acc[4];
#pragma unroll
      for (int g = 0; g < 4; ++g)
        acc[g] = __builtin_amdgcn_mfma_f32_16x16x32_bf16(
            a0[g], fx, (float4v){0.f, 0.f, 0.f, 0.f}, 0, 0, 0);
#pragma unroll
      for (int g = 0; g < 4; ++g)
        acc[g] = __builtin_amdgcn_mfma_f32_16x16x32_bf16(a1[g], fh0, acc[g], 0, 0, 0);
#pragma unroll
      for (int g = 0; g < 4; ++g)
        acc[g] = __builtin_amdgcn_mfma_f32_16x16x32_bf16(a2[g], fh1, acc[g], 0, 0, 0);

      // ---- pick this thread's element (reg-select tree) and activate ----
      float gsel[4];
#pragma unroll
      for (int g = 0; g < 4; ++g) {
        const float x01 = sel1 ? acc[g][1] : acc[g][0];
        const float x23 = sel1 ? acc[g][3] : acc[g][2];
        gsel[g] = sel2 ? x23 : x01;
      }
      const float iv = fsig(gsel[0]);
      const float fv = fsig(gsel[1]);
      const float gv = ftanh(gsel[2]);
      const float ov = fsig(gsel[3]);
      c = __builtin_fmaf(fv, c, iv * gv);
      const float h = ov * ftanh(c);
      h_lds[hb ^ 1][row][jh] = cvt_bf16(h);
      if (t == T_LEN - 1) hf[row][jh] = h;
      if (tt == TS - 1 && more) stage_write((ch + 1) & 1);
      __syncthreads();  // one barrier per step
    }
  }

  // ---- epilogue: out[b] = sigmoid(hT . fc_w + fc_b) ----
  if (tid < R) {
    float a = fc_b[0];
#pragma unroll
    for (int k = 0; k < 64; ++k) a += hf[tid][k] * fc_w[k];
    out[bBase + tid] = fsig(a);
  }
}
}  // namespace

extern "C" void kernel_launch(void* const* d_in, const int* in_sizes, int n_in,
                              void* d_out, int out_size, void* d_ws,
                              size_t ws_size, hipStream_t stream) {
  const float* x    = (const float*)d_in[0];
  const float* W_ih = (const float*)d_in[1];
  const float* W_hh = (const float*)d_in[2];
  const float* b_ih = (const float*)d_in[3];
  const float* b_hh = (const float*)d_in[4];
  const float* fc_w = (const float*)d_in[5];
  const float* fc_b = (const float*)d_in[6];
  float* out = (float*)d_out;

  const int B = in_sizes[0] / (T_LEN * 8);  // 2048
  lstm_split<<<dim3(B / R), dim3(256), 0, stream>>>(x, W_ih, W_hh, b_ih, b_hh,
                                                    fc_w, fc_b, out);
}